// Round 6
// baseline (523.270 us; speedup 1.0000x reference)
//
#include <hip/hip_runtime.h>
#include <math.h>

#define NB 65536

typedef short s16x8 __attribute__((ext_vector_type(8)));
typedef float f32x4 __attribute__((ext_vector_type(4)));

// ---------------- workspace layout (bytes) ----------------
#define SZ_TR     ((size_t)7*NB*32*2)            // packed bf16 traces (hi or lo)
#define OFF_TRHI  ((size_t)0)
#define OFF_TRLO  (OFF_TRHI + SZ_TR)
#define OFF_CONF  (OFF_TRLO + SZ_TR)
#define SZ_CONF   ((size_t)7*NB*4)
#define OFF_PART  (OFF_CONF + SZ_CONF)
#define SZ_PART   ((size_t)49*NB*4)
#define OFF_GATE  (OFF_PART + SZ_PART)
#define SZ_GATE   ((size_t)7*NB*4)
#define OFF_W1H   (OFF_GATE + SZ_GATE)           // composer W1 frags
#define SZ_W1F    ((size_t)7*4*2*64*16)
#define OFF_W1L   (OFF_W1H + SZ_W1F)
#define OFF_W2H   (OFF_W1L + SZ_W1F)
#define SZ_W2F    ((size_t)7*2*2*64*16)
#define OFF_W2L   (OFF_W2H + SZ_W2F)
#define OFF_G2H   (OFF_W2L + SZ_W2F)             // gen_W2 frags [7][2][2][64]u4
#define SZ_G2     ((size_t)7*2*2*64*16)
#define OFF_G2L   (OFF_G2H + SZ_G2)
// total ~75.5 MB (within proven budget)
//
// d_out scratch overlay (overwritten by colC at the end):
//   actHI : uint4[7*NB*8]  at outp byte 0          (58,720,256 B)
//   actLO : uint4[7*NB*8]  at byte 58,720,256
//   tn    : float[7*32*NB] at byte 117,440,512     (58,720,256 B)
//   => ends at 176,160,768 = NB*672*4 exactly (composed region)

// task t = l*3+p; src = FANO[l][p], par = FANO[l][(p+1)%3]
static __device__ const int T_SRC[21] = {0,1,2, 0,3,4, 0,5,6, 1,3,5, 1,4,6, 2,3,6, 2,4,5};
static __device__ const int T_PAR[21] = {1,2,0, 3,4,0, 5,6,0, 3,5,1, 4,6,1, 3,6,2, 4,5,2};

__device__ __forceinline__ float sigf(float x) { return 1.f / (1.f + expf(-x)); }

// round-to-nearest-even f32 -> bf16 (as uint16 in low bits)
__device__ __forceinline__ unsigned bfrnd(float x) {
    unsigned u = __builtin_bit_cast(unsigned, x);
    return (u + 0x7FFFu + ((u >> 16) & 1u)) >> 16;
}
__device__ __forceinline__ float bfval(unsigned h) {
    return __builtin_bit_cast(float, h << 16);
}

__device__ __forceinline__ f32x4 mfma16(s16x8 a, s16x8 b, f32x4 c) {
    return __builtin_amdgcn_mfma_f32_16x16x32_bf16(a, b, c, 0, 0, 0);
}

// pack 8 floats -> hi frag + lo frag (bf16 split)
__device__ __forceinline__ void pack8(const float* v, s16x8& hi, s16x8& lo) {
    uint4 hu, lu;
    unsigned h[8], l[8];
    #pragma unroll
    for (int i = 0; i < 8; ++i) {
        h[i] = bfrnd(v[i]);
        float rem = v[i] - bfval(h[i]);
        l[i] = bfrnd(rem);
    }
    hu.x = h[0] | (h[1] << 16); hu.y = h[2] | (h[3] << 16);
    hu.z = h[4] | (h[5] << 16); hu.w = h[6] | (h[7] << 16);
    lu.x = l[0] | (l[1] << 16); lu.y = l[2] | (l[3] << 16);
    lu.z = l[4] | (l[5] << 16); lu.w = l[6] | (l[7] << 16);
    hi = __builtin_bit_cast(s16x8, hu);
    lo = __builtin_bit_cast(s16x8, lu);
}

// ============ Kernel P: prepack MFMA A-fragments (composer W1/W2 + gen_W2) ============
__global__ __launch_bounds__(256, 4)
void colP(const float* __restrict__ c_W1, const float* __restrict__ c_W2,
          const float* __restrict__ gen_W2,
          uint4* __restrict__ w1h, uint4* __restrict__ w1l,
          uint4* __restrict__ w2h, uint4* __restrict__ w2l,
          uint4* __restrict__ g2h, uint4* __restrict__ g2l)
{
    const int e = blockIdx.x * 256 + threadIdx.x;
    if (e < 3584) {                       // composer W1 frags
        const int lane = e & 63, er = e >> 6;
        const int ks = er & 1, mt = (er >> 1) & 3, l = er >> 3;
        const int j  = mt * 16 + (lane & 15);
        const int k0 = ks * 32 + (lane >> 4) * 8;
        float v[8];
        #pragma unroll
        for (int jj = 0; jj < 8; ++jj) v[jj] = c_W1[((size_t)(l * 64 + k0 + jj)) * 64 + j];
        s16x8 hi, lo; pack8(v, hi, lo);
        w1h[e] = __builtin_bit_cast(uint4, hi);
        w1l[e] = __builtin_bit_cast(uint4, lo);
    } else if (e < 5376) {                // composer W2 frags
        const int e2 = e - 3584;
        const int lane = e2 & 63, er = e2 >> 6;
        const int ks2 = er & 1, mt2 = (er >> 1) & 1, l = er >> 2;
        const int d  = mt2 * 16 + (lane & 15);
        const int k0 = ks2 * 32 + (lane >> 4) * 8;
        float v[8];
        #pragma unroll
        for (int jj = 0; jj < 8; ++jj) v[jj] = c_W2[((size_t)(l * 64 + k0 + jj)) * 32 + d];
        s16x8 hi, lo; pack8(v, hi, lo);
        w2h[e2] = __builtin_bit_cast(uint4, hi);
        w2l[e2] = __builtin_bit_cast(uint4, lo);
    } else if (e < 7168) {                // gen_W2 frags (same transform, same shape)
        const int e2 = e - 5376;
        const int lane = e2 & 63, er = e2 >> 6;
        const int ks2 = er & 1, mt2 = (er >> 1) & 1, c = er >> 2;
        const int d  = mt2 * 16 + (lane & 15);
        const int k0 = ks2 * 32 + (lane >> 4) * 8;
        float v[8];
        #pragma unroll
        for (int jj = 0; jj < 8; ++jj) v[jj] = gen_W2[((size_t)(c * 64 + k0 + jj)) * 32 + d];
        s16x8 hi, lo; pack8(v, hi, lo);
        g2h[e2] = __builtin_bit_cast(uint4, hi);
        g2l[e2] = __builtin_bit_cast(uint4, lo);
    }
}

// ============ Kernel A1: scalar conf + gen1 + LN + act (R2-proven code path) ============
// gen2 removed -> live set ~85 regs. waves_per_eu(4,4): cap 128, no squeeze-to-64 spill
// (R0 pathology), no 104-reg occupancy collapse (R1 pathology).
__global__ __launch_bounds__(256) __attribute__((amdgpu_waves_per_eu(4, 4)))
void colA1(const float* __restrict__ z,
           const float* __restrict__ gen_W1, const float* __restrict__ gen_b1,
           const float* __restrict__ gen_g,  const float* __restrict__ gen_be,
           const float* __restrict__ cf_W1,  const float* __restrict__ cf_b1,
           const float* __restrict__ cf_W2,  const float* __restrict__ cf_b2,
           uint4* __restrict__ actHI, uint4* __restrict__ actLO,
           float* __restrict__ conf)
{
    const int c = blockIdx.x >> 8;
    const int b = ((blockIdx.x & 255) << 8) + threadIdx.x;

    float zv[14];
    {
        const float* zp = z + ((size_t)b * 7 + (size_t)c) * 14;
        #pragma unroll
        for (int i = 0; i < 7; ++i) {
            float2 u = *(const float2*)(zp + 2 * i);
            zv[2*i] = u.x; zv[2*i+1] = u.y;
        }
    }

    // ---- confidence head (proven) ----
    {
        float hc[32];
        const float* bp = cf_b1 + c * 32;
        #pragma unroll
        for (int k = 0; k < 32; ++k) hc[k] = bp[k];
        const float* W = cf_W1 + c * 14 * 32;
        for (int i = 0; i < 14; ++i) {
            const float zi = zv[i];
            const float* w = W + i * 32;
            #pragma unroll
            for (int k = 0; k < 32; ++k) hc[k] = fmaf(zi, w[k], hc[k]);
        }
        float cl = cf_b2[c];
        const float* w2 = cf_W2 + c * 32;
        #pragma unroll
        for (int k = 0; k < 32; ++k) cl = fmaf(fmaxf(hc[k], 0.f), w2[k], cl);
        conf[(size_t)c * NB + b] = sigf(cl);
    }

    // ---- gen1: h = z @ gen_W1[c] + b1 (proven one-pass) ----
    float h[64];
    {
        const float* bp = gen_b1 + c * 64;
        #pragma unroll
        for (int j = 0; j < 64; ++j) h[j] = bp[j];
        const float* W = gen_W1 + c * 14 * 64;
        for (int i = 0; i < 14; ++i) {
            const float zi = zv[i];
            const float* w = W + i * 64;
            #pragma unroll
            for (int j = 0; j < 64; ++j) h[j] = fmaf(zi, w[j], h[j]);
        }
    }
    // ---- LayerNorm (proven) ----
    {
        float m = 0.f;
        #pragma unroll
        for (int j = 0; j < 64; ++j) m += h[j];
        m *= (1.f / 64.f);
        float v = 0.f;
        #pragma unroll
        for (int j = 0; j < 64; ++j) { float d = h[j] - m; v = fmaf(d, d, v); }
        v *= (1.f / 64.f);
        const float rs = 1.f / sqrtf(v + 1e-5f);
        const float* gp = gen_g  + c * 64;
        const float* bp = gen_be + c * 64;
        #pragma unroll
        for (int j = 0; j < 64; ++j) h[j] = (h[j] - m) * rs * gp[j] + bp[j];
    }
    // ---- colony-specific activation (exact lib funcs — proven) ----
    switch (c) {
        case 0:
            #pragma unroll
            for (int j = 0; j < 64; ++j) h[j] = fmaxf(h[j], 0.f);
            break;
        case 1:
            #pragma unroll
            for (int j = 0; j < 64; ++j) h[j] = tanhf(h[j]);
            break;
        case 2:
            #pragma unroll
            for (int j = 0; j < 64; ++j) h[j] = 0.5f * h[j] * (1.f + erff(h[j] * 0.70710678118654752f));
            break;
        case 3:
            #pragma unroll
            for (int j = 0; j < 64; ++j) h[j] = h[j] * sigf(h[j]);
            break;
        case 4:
            #pragma unroll
            for (int j = 0; j < 64; ++j) h[j] = fmaxf(h[j], 0.f) + log1pf(expf(-fabsf(h[j])));
            break;
        case 5:
            #pragma unroll
            for (int j = 0; j < 64; ++j) h[j] = sigf(h[j]);
            break;
        default:
            #pragma unroll
            for (int j = 0; j < 64; ++j) h[j] = fminf(fmaxf(h[j], -1.f), 1.f);
            break;
    }
    // ---- pack act to bf16 hi/lo chunks (proven pack pattern; chunk k = act[8k..8k+7]) ----
    {
        const size_t abase = ((size_t)c * NB + b) * 8;
        #pragma unroll
        for (int k = 0; k < 8; ++k) {
            unsigned hw[4], lw[4];
            #pragma unroll
            for (int i = 0; i < 4; ++i) {
                const int e = 8 * k + 2 * i;
                unsigned h0 = bfrnd(h[e]), h1 = bfrnd(h[e+1]);
                float r0 = h[e]   - bfval(h0);
                float r1 = h[e+1] - bfval(h1);
                hw[i] = h0 | (h1 << 16);
                lw[i] = bfrnd(r0) | (bfrnd(r1) << 16);
            }
            uint4 u; u.x = hw[0]; u.y = hw[1]; u.z = hw[2]; u.w = hw[3];
            actHI[abase + k] = u;
            uint4 v; v.x = lw[0]; v.y = lw[1]; v.z = lw[2]; v.w = lw[3];
            actLO[abase + k] = v;
        }
    }
}

// ============ Kernel A2: gen2 via MFMA (colC-clone mechanics only) ============
// B-frags loaded straight from act chunks (same pattern as colC's trHI loads).
// No LDS. Output tn stored fp32 in [c][d][b] planes (coalesced across b).
__global__ __launch_bounds__(256, 4)
void colA2(const uint4* __restrict__ actHI, const uint4* __restrict__ actLO,
           const uint4* __restrict__ g2h, const uint4* __restrict__ g2l,
           const float* __restrict__ gen_b2,
           float* __restrict__ tn_ws)
{
    const int wave = threadIdx.x >> 6;
    const int lane = threadIdx.x & 63;
    const int q    = lane >> 4;
    const int bl   = lane & 15;
    const int c    = blockIdx.x >> 6;                       // 7*64 blocks
    const int base = ((blockIdx.x & 63) << 10) + (wave << 8);

    s16x8 a2h[2][2], a2l[2][2];
    #pragma unroll
    for (int mt = 0; mt < 2; ++mt)
        #pragma unroll
        for (int ks = 0; ks < 2; ++ks) {
            a2h[mt][ks] = __builtin_bit_cast(s16x8, g2h[((c * 2 + mt) * 2 + ks) * 64 + lane]);
            a2l[mt][ks] = __builtin_bit_cast(s16x8, g2l[((c * 2 + mt) * 2 + ks) * 64 + lane]);
        }
    f32x4 b2v[2];
    {
        const f32x4* p2 = (const f32x4*)(gen_b2 + (size_t)c * 32);
        #pragma unroll
        for (int mt = 0; mt < 2; ++mt) b2v[mt] = p2[4 * mt + q];
    }

    for (int it = 0; it < 16; ++it) {
        const int bg = base + it * 16 + bl;
        const size_t ab = ((size_t)c * NB + bg) * 8;

        // B-frags: lane (q,bl) holds act[k = 32*ks2 + 8q + j] of batch bg
        s16x8 bh0 = __builtin_bit_cast(s16x8, actHI[ab + q]);
        s16x8 bl0 = __builtin_bit_cast(s16x8, actLO[ab + q]);
        s16x8 bh1 = __builtin_bit_cast(s16x8, actHI[ab + 4 + q]);
        s16x8 bl1 = __builtin_bit_cast(s16x8, actLO[ab + 4 + q]);

        f32x4 d0 = {0.f,0.f,0.f,0.f}, d1 = {0.f,0.f,0.f,0.f};
        // ks2 = 0 (split-3)
        d0 = mfma16(a2h[0][0], bh0, d0);
        d0 = mfma16(a2h[0][0], bl0, d0);
        d0 = mfma16(a2l[0][0], bh0, d0);
        d1 = mfma16(a2h[1][0], bh0, d1);
        d1 = mfma16(a2h[1][0], bl0, d1);
        d1 = mfma16(a2l[1][0], bh0, d1);
        // ks2 = 1
        d0 = mfma16(a2h[0][1], bh1, d0);
        d0 = mfma16(a2h[0][1], bl1, d0);
        d0 = mfma16(a2l[0][1], bh1, d0);
        d1 = mfma16(a2h[1][1], bh1, d1);
        d1 = mfma16(a2h[1][1], bl1, d1);
        d1 = mfma16(a2l[1][1], bh1, d1);

        d0 += b2v[0];
        d1 += b2v[1];

        // l2norm over 32 d's (colC-proven shfl reduction)
        float ss = 0.f;
        #pragma unroll
        for (int r = 0; r < 4; ++r) { ss = fmaf(d0[r], d0[r], ss); ss = fmaf(d1[r], d1[r], ss); }
        ss += __shfl_xor(ss, 16);
        ss += __shfl_xor(ss, 32);
        const float inv = 1.f / fmaxf(sqrtf(ss), 1e-12f);

        // tn fp32 store: d = 16*mt + 4q + r at plane (c*32+d)*NB + bg
        #pragma unroll
        for (int r = 0; r < 4; ++r)
            tn_ws[((size_t)(c * 32 + 4 * q + r)) * NB + bg] = d0[r] * inv;
        #pragma unroll
        for (int r = 0; r < 4; ++r)
            tn_ws[((size_t)(c * 32 + 16 + 4 * q + r)) * NB + bg] = d1[r] * inv;
    }
}

// ============ Kernel B1: scalar trace pack + fp32 gate partials (R2-proven code) ============
__global__ __launch_bounds__(256, 4)
void colB1(const float* __restrict__ tn_ws, const float* __restrict__ g_W,
           uint4* __restrict__ trHI, uint4* __restrict__ trLO,
           float* __restrict__ part)
{
    const int c = blockIdx.x >> 8;
    const int b = ((blockIdx.x & 255) << 8) + threadIdx.x;

    float tn[32];
    #pragma unroll
    for (int d = 0; d < 32; ++d) tn[d] = tn_ws[((size_t)(c * 32 + d)) * NB + b];

    // ---- packed bf16 hi/lo trace store (R2 verbatim) ----
    {
        const size_t base = ((size_t)c * NB + b) * 4;
        #pragma unroll
        for (int k = 0; k < 4; ++k) {
            unsigned hw[4], lw[4];
            #pragma unroll
            for (int i = 0; i < 4; ++i) {
                const int e = 8 * k + 2 * i;
                unsigned h0 = bfrnd(tn[e]),   h1 = bfrnd(tn[e+1]);
                float r0 = tn[e]   - bfval(h0);
                float r1 = tn[e+1] - bfval(h1);
                hw[i] = h0 | (h1 << 16);
                lw[i] = bfrnd(r0) | (bfrnd(r1) << 16);
            }
            uint4 u; u.x = hw[0]; u.y = hw[1]; u.z = hw[2]; u.w = hw[3];
            trHI[base + k] = u;
            uint4 v; v.x = lw[0]; v.y = lw[1]; v.z = lw[2]; v.w = lw[3];
            trLO[base + k] = v;
        }
    }
    // ---- gate partials fp32 (R2 verbatim) ----
    {
        float p[7] = {0.f,0.f,0.f,0.f,0.f,0.f,0.f};
        for (int k = 0; k < 32; ++k) {
            const float v = tn[k];
            const float* w = g_W + (c * 32 + k) * 7;
            #pragma unroll
            for (int l2 = 0; l2 < 7; ++l2) p[l2] = fmaf(v, w[l2], p[l2]);
        }
        #pragma unroll
        for (int l2 = 0; l2 < 7; ++l2) part[((size_t)(c * 7 + l2)) * NB + b] = p[l2];
    }
}

// ============ Kernel B2: gates + comp_conf output (R2 verbatim) ============
__global__ __launch_bounds__(256, 4)
void colB2(const float* __restrict__ g_b,
           const float* __restrict__ part, const float* __restrict__ conf,
           float* __restrict__ gates, float* __restrict__ out2)
{
    const int b = blockIdx.x * 256 + threadIdx.x;

    float g[7];
    #pragma unroll
    for (int l = 0; l < 7; ++l) g[l] = g_b[l];
    for (int c = 0; c < 7; ++c) {
        #pragma unroll
        for (int l = 0; l < 7; ++l) g[l] += part[((size_t)(c * 7 + l)) * NB + b];
    }
    #pragma unroll
    for (int l = 0; l < 7; ++l) {
        g[l] = sigf(g[l]);
        gates[(size_t)l * NB + b] = g[l];
    }

    float cf[7];
    #pragma unroll
    for (int c = 0; c < 7; ++c) cf[c] = conf[(size_t)c * NB + b];

    float* op = out2 + (size_t)b * 21;
    #pragma unroll
    for (int t = 0; t < 21; ++t) {
        const int l = t / 3;
        const float gl = g[l];
        op[t] = (gl >= 0.3f) ? cf[T_SRC[t]] * cf[T_PAR[t]] * gl : 0.f;
    }
}

// ============ Kernel C: composers via split-bf16 MFMA (unchanged, proven) ============
__global__ __launch_bounds__(256, 2)
void colC(const uint4* __restrict__ trHI, const uint4* __restrict__ trLO,
          const float* __restrict__ gates,
          const uint4* __restrict__ w1fh, const uint4* __restrict__ w1fl,
          const uint4* __restrict__ w2fh, const uint4* __restrict__ w2fl,
          const float* __restrict__ c_b1,
          const float* __restrict__ c_g,  const float* __restrict__ c_be,
          const float* __restrict__ c_b2, float* __restrict__ out)
{
    __shared__ float lds[4][16 * 68];   // per-wave CH^T buffer [b][j], stride 68 (pad)

    const int wave = threadIdx.x >> 6;
    const int lane = threadIdx.x & 63;
    const int q    = lane >> 4;         // quad
    const int bl   = lane & 15;         // batch-in-tile (MFMA column)

    const int t   = blockIdx.x >> 6;    // 64 blocks per task
    const int l   = t / 3;
    const int src = T_SRC[t];
    const int par = T_PAR[t];
    const int base = ((blockIdx.x & 63) << 10) + (wave << 8);   // wave's batch base

    s16x8 w1h[4][2], w1l[4][2], w2h[2][2], w2l[2][2];
    #pragma unroll
    for (int mt = 0; mt < 4; ++mt)
        #pragma unroll
        for (int ks = 0; ks < 2; ++ks) {
            w1h[mt][ks] = __builtin_bit_cast(s16x8, w1fh[((l * 4 + mt) * 2 + ks) * 64 + lane]);
            w1l[mt][ks] = __builtin_bit_cast(s16x8, w1fl[((l * 4 + mt) * 2 + ks) * 64 + lane]);
        }
    #pragma unroll
    for (int mt = 0; mt < 2; ++mt)
        #pragma unroll
        for (int ks = 0; ks < 2; ++ks) {
            w2h[mt][ks] = __builtin_bit_cast(s16x8, w2fh[((l * 2 + mt) * 2 + ks) * 64 + lane]);
            w2l[mt][ks] = __builtin_bit_cast(s16x8, w2fl[((l * 2 + mt) * 2 + ks) * 64 + lane]);
        }

    f32x4 b1v[4], gv[4], bev[4], b2v[2];
    {
        const f32x4* p1 = (const f32x4*)(c_b1 + (size_t)l * 64);
        const f32x4* pg = (const f32x4*)(c_g  + (size_t)l * 64);
        const f32x4* pb = (const f32x4*)(c_be + (size_t)l * 64);
        #pragma unroll
        for (int mt = 0; mt < 4; ++mt) {
            b1v[mt] = p1[4 * mt + q]; gv[mt] = pg[4 * mt + q]; bev[mt] = pb[4 * mt + q];
        }
        const f32x4* p2 = (const f32x4*)(c_b2 + (size_t)l * 32);
        #pragma unroll
        for (int mt = 0; mt < 2; ++mt) b2v[mt] = p2[4 * mt + q];
    }

    float* ldsw = &lds[wave][0];

    for (int it = 0; it < 16; ++it) {
        const int bg = base + it * 16 + bl;

        const size_t sb = ((size_t)src * NB + bg) * 4 + q;
        const size_t pb = ((size_t)par * NB + bg) * 4 + q;
        s16x8 bsh = __builtin_bit_cast(s16x8, trHI[sb]);
        s16x8 bsl = __builtin_bit_cast(s16x8, trLO[sb]);
        s16x8 bph = __builtin_bit_cast(s16x8, trHI[pb]);
        s16x8 bpl = __builtin_bit_cast(s16x8, trLO[pb]);
        const float gate = gates[(size_t)l * NB + bg];

        f32x4 acc[4];
        #pragma unroll
        for (int mt = 0; mt < 4; ++mt) {
            f32x4 a = {0.f, 0.f, 0.f, 0.f};
            a = mfma16(w1h[mt][0], bsh, a);
            a = mfma16(w1h[mt][0], bsl, a);
            a = mfma16(w1l[mt][0], bsh, a);
            a = mfma16(w1h[mt][1], bph, a);
            a = mfma16(w1h[mt][1], bpl, a);
            a = mfma16(w1l[mt][1], bph, a);
            acc[mt] = a;
        }
        #pragma unroll
        for (int mt = 0; mt < 4; ++mt) acc[mt] += b1v[mt];

        float s = 0.f;
        #pragma unroll
        for (int mt = 0; mt < 4; ++mt)
            #pragma unroll
            for (int r = 0; r < 4; ++r) s += acc[mt][r];
        s += __shfl_xor(s, 16);
        s += __shfl_xor(s, 32);
        const float mean = s * (1.f / 64.f);
        float v = 0.f;
        #pragma unroll
        for (int mt = 0; mt < 4; ++mt)
            #pragma unroll
            for (int r = 0; r < 4; ++r) { float d = acc[mt][r] - mean; v = fmaf(d, d, v); }
        v += __shfl_xor(v, 16);
        v += __shfl_xor(v, 32);
        const float rs = 1.f / sqrtf(v * (1.f / 64.f) + 1e-5f);

        #pragma unroll
        for (int mt = 0; mt < 4; ++mt) {
            f32x4 x;
            #pragma unroll
            for (int r = 0; r < 4; ++r)
                x[r] = fmaxf(fmaf((acc[mt][r] - mean) * rs, gv[mt][r], bev[mt][r]), 0.f);
            *(f32x4*)&ldsw[bl * 68 + 16 * mt + 4 * q] = x;
        }

        f32x4 d0 = {0.f,0.f,0.f,0.f}, d1 = {0.f,0.f,0.f,0.f};
        #pragma unroll
        for (int ks2 = 0; ks2 < 2; ++ks2) {
            f32x4 c0 = *(const f32x4*)&ldsw[bl * 68 + 32 * ks2 + 8 * q];
            f32x4 c1 = *(const f32x4*)&ldsw[bl * 68 + 32 * ks2 + 8 * q + 4];
            float vv[8] = {c0[0], c0[1], c0[2], c0[3], c1[0], c1[1], c1[2], c1[3]};
            s16x8 chh, chl; pack8(vv, chh, chl);
            d0 = mfma16(w2h[0][ks2], chh, d0);
            d0 = mfma16(w2h[0][ks2], chl, d0);
            d0 = mfma16(w2l[0][ks2], chh, d0);
            d1 = mfma16(w2h[1][ks2], chh, d1);
            d1 = mfma16(w2h[1][ks2], chl, d1);
            d1 = mfma16(w2l[1][ks2], chh, d1);
        }
        d0 += b2v[0];
        d1 += b2v[1];

        float ss = 0.f;
        #pragma unroll
        for (int r = 0; r < 4; ++r) { ss = fmaf(d0[r], d0[r], ss); ss = fmaf(d1[r], d1[r], ss); }
        ss += __shfl_xor(ss, 16);
        ss += __shfl_xor(ss, 32);
        const float inv   = 1.f / fmaxf(sqrtf(ss), 1e-12f);
        const float scale = (gate >= 0.3f) ? gate * inv : 0.f;

        float* op = out + (size_t)bg * 672 + t * 32;
        f32x4 o0, o1;
        #pragma unroll
        for (int r = 0; r < 4; ++r) { o0[r] = d0[r] * scale; o1[r] = d1[r] * scale; }
        *(f32x4*)(op + 4 * q)      = o0;
        *(f32x4*)(op + 16 + 4 * q) = o1;
    }
}

extern "C" void kernel_launch(void* const* d_in, const int* in_sizes, int n_in,
                              void* d_out, int out_size, void* d_ws, size_t ws_size,
                              hipStream_t stream) {
    const float* z      = (const float*)d_in[0];
    const float* gen_W1 = (const float*)d_in[1];
    const float* gen_b1 = (const float*)d_in[2];
    const float* gen_g  = (const float*)d_in[3];
    const float* gen_be = (const float*)d_in[4];
    const float* gen_W2 = (const float*)d_in[5];
    const float* gen_b2 = (const float*)d_in[6];
    const float* cf_W1  = (const float*)d_in[7];
    const float* cf_b1  = (const float*)d_in[8];
    const float* cf_W2  = (const float*)d_in[9];
    const float* cf_b2  = (const float*)d_in[10];
    const float* g_W    = (const float*)d_in[11];
    const float* g_b    = (const float*)d_in[12];
    const float* c_W1   = (const float*)d_in[13];
    const float* c_b1   = (const float*)d_in[14];
    const float* c_g    = (const float*)d_in[15];
    const float* c_be   = (const float*)d_in[16];
    const float* c_W2   = (const float*)d_in[17];
    const float* c_b2   = (const float*)d_in[18];

    char* wsb = (char*)d_ws;
    uint4* trHI  = (uint4*)(wsb + OFF_TRHI);
    uint4* trLO  = (uint4*)(wsb + OFF_TRLO);
    float* conf  = (float*)(wsb + OFF_CONF);
    float* part  = (float*)(wsb + OFF_PART);
    float* gates = (float*)(wsb + OFF_GATE);
    uint4* w1fh  = (uint4*)(wsb + OFF_W1H);
    uint4* w1fl  = (uint4*)(wsb + OFF_W1L);
    uint4* w2fh  = (uint4*)(wsb + OFF_W2H);
    uint4* w2fl  = (uint4*)(wsb + OFF_W2L);
    uint4* g2h   = (uint4*)(wsb + OFF_G2H);
    uint4* g2l   = (uint4*)(wsb + OFF_G2L);

    float* outp = (float*)d_out;
    float* out2 = outp + (size_t)NB * 672;

    // d_out scratch overlay (consumed before colC overwrites the composed region)
    uint4* actHI = (uint4*)outp;                          // 58,720,256 B
    uint4* actLO = actHI + (size_t)7 * NB * 8;            // 58,720,256 B
    float* tn_ws = outp + (size_t)29360128;               // 58,720,256 B, ends at NB*672*4

    colP<<<dim3(28), dim3(256), 0, stream>>>(
        c_W1, c_W2, gen_W2, w1fh, w1fl, w2fh, w2fl, g2h, g2l);
    colA1<<<dim3(7 * 256), dim3(256), 0, stream>>>(
        z, gen_W1, gen_b1, gen_g, gen_be, cf_W1, cf_b1, cf_W2, cf_b2,
        actHI, actLO, conf);
    colA2<<<dim3(7 * 64), dim3(256), 0, stream>>>(
        actHI, actLO, g2h, g2l, gen_b2, tn_ws);
    colB1<<<dim3(7 * 256), dim3(256), 0, stream>>>(
        tn_ws, g_W, trHI, trLO, part);
    colB2<<<dim3(256), dim3(256), 0, stream>>>(g_b, part, conf, gates, out2);
    colC<<<dim3(21 * 64), dim3(256), 0, stream>>>(
        trHI, trLO, gates, w1fh, w1fl, w2fh, w2fl,
        c_b1, c_g, c_be, c_b2, outp);
}

// Round 7
// 485.421 us; speedup vs baseline: 1.0780x; 1.0780x over previous
//
#include <hip/hip_runtime.h>
#include <math.h>

#define NB 65536

typedef short s16x8 __attribute__((ext_vector_type(8)));
typedef float f32x4 __attribute__((ext_vector_type(4)));

// ---------------- workspace layout (bytes) ----------------
#define SZ_TR     ((size_t)7*NB*32*2)            // packed bf16 traces (hi or lo)
#define OFF_TRHI  ((size_t)0)
#define OFF_TRLO  (OFF_TRHI + SZ_TR)
#define OFF_CONF  (OFF_TRLO + SZ_TR)
#define SZ_CONF   ((size_t)7*NB*4)
#define OFF_PART  (OFF_CONF + SZ_CONF)
#define SZ_PART   ((size_t)49*NB*4)
#define OFF_GATE  (OFF_PART + SZ_PART)
#define SZ_GATE   ((size_t)7*NB*4)
#define OFF_W1H   (OFF_GATE + SZ_GATE)           // composer W1 frags
#define SZ_W1F    ((size_t)7*4*2*64*16)
#define OFF_W1L   (OFF_W1H + SZ_W1F)
#define OFF_W2H   (OFF_W1L + SZ_W1F)
#define SZ_W2F    ((size_t)7*2*2*64*16)
#define OFF_W2L   (OFF_W2H + SZ_W2F)
#define OFF_G2H   (OFF_W2L + SZ_W2F)             // gen_W2 frags [7][2][2][64]u4
#define SZ_G2     ((size_t)7*2*2*64*16)
#define OFF_G2L   (OFF_G2H + SZ_G2)
// total ~75.5 MB (within proven budget)
//
// d_out scratch overlay (overwritten by colC at the end):
//   actHI : uint4[7*NB*8]  at outp byte 0          (58,720,256 B)
//   actLO : uint4[7*NB*8]  at byte 58,720,256
//   tn    : float[7*32*NB] at byte 117,440,512     (58,720,256 B)
//   => ends at 176,160,768 = NB*672*4 exactly (composed region)

// task t = l*3+p; src = FANO[l][p], par = FANO[l][(p+1)%3]
static __device__ const int T_SRC[21] = {0,1,2, 0,3,4, 0,5,6, 1,3,5, 1,4,6, 2,3,6, 2,4,5};
static __device__ const int T_PAR[21] = {1,2,0, 3,4,0, 5,6,0, 3,5,1, 4,6,1, 3,6,2, 4,5,2};

__device__ __forceinline__ float sigf(float x) { return 1.f / (1.f + expf(-x)); }

// round-to-nearest-even f32 -> bf16 (as uint16 in low bits)
__device__ __forceinline__ unsigned bfrnd(float x) {
    unsigned u = __builtin_bit_cast(unsigned, x);
    return (u + 0x7FFFu + ((u >> 16) & 1u)) >> 16;
}
__device__ __forceinline__ float bfval(unsigned h) {
    return __builtin_bit_cast(float, h << 16);
}

__device__ __forceinline__ f32x4 mfma16(s16x8 a, s16x8 b, f32x4 c) {
    return __builtin_amdgcn_mfma_f32_16x16x32_bf16(a, b, c, 0, 0, 0);
}

// pack 8 floats -> hi frag + lo frag (bf16 split)
__device__ __forceinline__ void pack8(const float* v, s16x8& hi, s16x8& lo) {
    uint4 hu, lu;
    unsigned h[8], l[8];
    #pragma unroll
    for (int i = 0; i < 8; ++i) {
        h[i] = bfrnd(v[i]);
        float rem = v[i] - bfval(h[i]);
        l[i] = bfrnd(rem);
    }
    hu.x = h[0] | (h[1] << 16); hu.y = h[2] | (h[3] << 16);
    hu.z = h[4] | (h[5] << 16); hu.w = h[6] | (h[7] << 16);
    lu.x = l[0] | (l[1] << 16); lu.y = l[2] | (l[3] << 16);
    lu.z = l[4] | (l[5] << 16); lu.w = l[6] | (l[7] << 16);
    hi = __builtin_bit_cast(s16x8, hu);
    lo = __builtin_bit_cast(s16x8, lu);
}

// colony-specific activation applied in-place to N values (exact lib funcs, R2-proven)
template <int N>
__device__ __forceinline__ void actN(int c, float* a) {
    switch (c) {
        case 0:
            #pragma unroll
            for (int u = 0; u < N; ++u) a[u] = fmaxf(a[u], 0.f);
            break;
        case 1:
            #pragma unroll
            for (int u = 0; u < N; ++u) a[u] = tanhf(a[u]);
            break;
        case 2:
            #pragma unroll
            for (int u = 0; u < N; ++u) a[u] = 0.5f * a[u] * (1.f + erff(a[u] * 0.70710678118654752f));
            break;
        case 3:
            #pragma unroll
            for (int u = 0; u < N; ++u) a[u] = a[u] * sigf(a[u]);
            break;
        case 4:
            #pragma unroll
            for (int u = 0; u < N; ++u) a[u] = fmaxf(a[u], 0.f) + log1pf(expf(-fabsf(a[u])));
            break;
        case 5:
            #pragma unroll
            for (int u = 0; u < N; ++u) a[u] = sigf(a[u]);
            break;
        default:
            #pragma unroll
            for (int u = 0; u < N; ++u) a[u] = fminf(fmaxf(a[u], -1.f), 1.f);
            break;
    }
}

// ============ Kernel P: prepack MFMA A-fragments (composer W1/W2 + gen_W2) ============
__global__ __launch_bounds__(256, 4)
void colP(const float* __restrict__ c_W1, const float* __restrict__ c_W2,
          const float* __restrict__ gen_W2,
          uint4* __restrict__ w1h, uint4* __restrict__ w1l,
          uint4* __restrict__ w2h, uint4* __restrict__ w2l,
          uint4* __restrict__ g2h, uint4* __restrict__ g2l)
{
    const int e = blockIdx.x * 256 + threadIdx.x;
    if (e < 3584) {                       // composer W1 frags
        const int lane = e & 63, er = e >> 6;
        const int ks = er & 1, mt = (er >> 1) & 3, l = er >> 3;
        const int j  = mt * 16 + (lane & 15);
        const int k0 = ks * 32 + (lane >> 4) * 8;
        float v[8];
        #pragma unroll
        for (int jj = 0; jj < 8; ++jj) v[jj] = c_W1[((size_t)(l * 64 + k0 + jj)) * 64 + j];
        s16x8 hi, lo; pack8(v, hi, lo);
        w1h[e] = __builtin_bit_cast(uint4, hi);
        w1l[e] = __builtin_bit_cast(uint4, lo);
    } else if (e < 5376) {                // composer W2 frags
        const int e2 = e - 3584;
        const int lane = e2 & 63, er = e2 >> 6;
        const int ks2 = er & 1, mt2 = (er >> 1) & 1, l = er >> 2;
        const int d  = mt2 * 16 + (lane & 15);
        const int k0 = ks2 * 32 + (lane >> 4) * 8;
        float v[8];
        #pragma unroll
        for (int jj = 0; jj < 8; ++jj) v[jj] = c_W2[((size_t)(l * 64 + k0 + jj)) * 32 + d];
        s16x8 hi, lo; pack8(v, hi, lo);
        w2h[e2] = __builtin_bit_cast(uint4, hi);
        w2l[e2] = __builtin_bit_cast(uint4, lo);
    } else if (e < 7168) {                // gen_W2 frags (same transform, same shape)
        const int e2 = e - 5376;
        const int lane = e2 & 63, er = e2 >> 6;
        const int ks2 = er & 1, mt2 = (er >> 1) & 1, c = er >> 2;
        const int d  = mt2 * 16 + (lane & 15);
        const int k0 = ks2 * 32 + (lane >> 4) * 8;
        float v[8];
        #pragma unroll
        for (int jj = 0; jj < 8; ++jj) v[jj] = gen_W2[((size_t)(c * 64 + k0 + jj)) * 32 + d];
        s16x8 hi, lo; pack8(v, hi, lo);
        g2h[e2] = __builtin_bit_cast(uint4, hi);
        g2l[e2] = __builtin_bit_cast(uint4, lo);
    }
}

// ============ Kernel A1: scalar conf + gen1 + LN + act, TWO-PASS (R2-proven structure) ============
// R6 showed the h[64] live range spills again under any allocator knob (VGPR=64,
// +80MB scratch writes). Fix structurally: pass 1 computes gen1 chunk-wise keeping
// only sum/ssq; pass 2 RECOMPUTES chunk-wise (+896 FMA ~ 7us issue), applies LN +
// exact activation, packs each 16-chunk straight to actHI/actLO. Live set ~50 regs.
__global__ __launch_bounds__(256, 4)
void colA1(const float* __restrict__ z,
           const float* __restrict__ gen_W1, const float* __restrict__ gen_b1,
           const float* __restrict__ gen_g,  const float* __restrict__ gen_be,
           const float* __restrict__ cf_W1,  const float* __restrict__ cf_b1,
           const float* __restrict__ cf_W2,  const float* __restrict__ cf_b2,
           uint4* __restrict__ actHI, uint4* __restrict__ actLO,
           float* __restrict__ conf)
{
    const int c = blockIdx.x >> 8;
    const int b = ((blockIdx.x & 255) << 8) + threadIdx.x;

    float zv[14];
    {
        const float* zp = z + ((size_t)b * 7 + (size_t)c) * 14;
        #pragma unroll
        for (int i = 0; i < 7; ++i) {
            float2 u = *(const float2*)(zp + 2 * i);
            zv[2*i] = u.x; zv[2*i+1] = u.y;
        }
    }

    // ---- confidence head (proven) ----
    {
        float hc[32];
        const float* bp = cf_b1 + c * 32;
        #pragma unroll
        for (int k = 0; k < 32; ++k) hc[k] = bp[k];
        const float* W = cf_W1 + c * 14 * 32;
        for (int i = 0; i < 14; ++i) {
            const float zi = zv[i];
            const float* w = W + i * 32;
            #pragma unroll
            for (int k = 0; k < 32; ++k) hc[k] = fmaf(zi, w[k], hc[k]);
        }
        float cl = cf_b2[c];
        const float* w2 = cf_W2 + c * 32;
        #pragma unroll
        for (int k = 0; k < 32; ++k) cl = fmaf(fmaxf(hc[k], 0.f), w2[k], cl);
        conf[(size_t)c * NB + b] = sigf(cl);
    }

    const float* W1p = gen_W1 + c * 14 * 64;
    const float* b1p = gen_b1 + c * 64;

    // ---- pass 1: LN statistics (chunked h, only sum/sumsq live across chunks) ----
    float sum = 0.f, ssq = 0.f;
    #pragma unroll 1
    for (int j0 = 0; j0 < 64; j0 += 16) {
        float hj[16];
        #pragma unroll
        for (int u = 0; u < 16; ++u) hj[u] = b1p[j0 + u];
        #pragma unroll
        for (int i = 0; i < 14; ++i) {
            const float zi = zv[i];
            const float* w = W1p + i * 64 + j0;
            #pragma unroll
            for (int u = 0; u < 16; ++u) hj[u] = fmaf(zi, w[u], hj[u]);
        }
        #pragma unroll
        for (int u = 0; u < 16; ++u) { sum += hj[u]; ssq = fmaf(hj[u], hj[u], ssq); }
    }
    const float mean = sum * (1.f / 64.f);
    const float var  = fmaxf(ssq * (1.f / 64.f) - mean * mean, 0.f);
    const float rs   = 1.f / sqrtf(var + 1e-5f);

    // opaque fence: make pass-2 recompute non-CSE-able against pass 1 (R2-proven)
    #pragma unroll
    for (int i = 0; i < 14; ++i) asm volatile("" : "+v"(zv[i]));

    // ---- pass 2: recompute chunk-wise, LN + act, pack straight to act chunks ----
    {
        const float* gp  = gen_g  + c * 64;
        const float* bep = gen_be + c * 64;
        const size_t abase = ((size_t)c * NB + b) * 8;
        #pragma unroll 1
        for (int j0 = 0; j0 < 64; j0 += 16) {
            float a16[16];
            #pragma unroll
            for (int u = 0; u < 16; ++u) a16[u] = b1p[j0 + u];
            #pragma unroll
            for (int i = 0; i < 14; ++i) {
                const float zi = zv[i];
                const float* w = W1p + i * 64 + j0;
                #pragma unroll
                for (int u = 0; u < 16; ++u) a16[u] = fmaf(zi, w[u], a16[u]);
            }
            #pragma unroll
            for (int u = 0; u < 16; ++u)
                a16[u] = fmaf((a16[u] - mean) * rs, gp[j0 + u], bep[j0 + u]);
            actN<16>(c, a16);
            // pack two 8-chunks (chunk k covers act[8k..8k+7])
            #pragma unroll
            for (int half = 0; half < 2; ++half) {
                unsigned hw[4], lw[4];
                #pragma unroll
                for (int i = 0; i < 4; ++i) {
                    const int e = half * 8 + 2 * i;
                    unsigned h0 = bfrnd(a16[e]), h1 = bfrnd(a16[e+1]);
                    float r0 = a16[e]   - bfval(h0);
                    float r1 = a16[e+1] - bfval(h1);
                    hw[i] = h0 | (h1 << 16);
                    lw[i] = bfrnd(r0) | (bfrnd(r1) << 16);
                }
                uint4 u4; u4.x = hw[0]; u4.y = hw[1]; u4.z = hw[2]; u4.w = hw[3];
                actHI[abase + (j0 >> 3) + half] = u4;
                uint4 v4; v4.x = lw[0]; v4.y = lw[1]; v4.z = lw[2]; v4.w = lw[3];
                actLO[abase + (j0 >> 3) + half] = v4;
            }
        }
    }
}

// ============ Kernel A2: gen2 via MFMA (R6-proven) ============
__global__ __launch_bounds__(256, 4)
void colA2(const uint4* __restrict__ actHI, const uint4* __restrict__ actLO,
           const uint4* __restrict__ g2h, const uint4* __restrict__ g2l,
           const float* __restrict__ gen_b2,
           float* __restrict__ tn_ws)
{
    const int wave = threadIdx.x >> 6;
    const int lane = threadIdx.x & 63;
    const int q    = lane >> 4;
    const int bl   = lane & 15;
    const int c    = blockIdx.x >> 6;                       // 7*64 blocks
    const int base = ((blockIdx.x & 63) << 10) + (wave << 8);

    s16x8 a2h[2][2], a2l[2][2];
    #pragma unroll
    for (int mt = 0; mt < 2; ++mt)
        #pragma unroll
        for (int ks = 0; ks < 2; ++ks) {
            a2h[mt][ks] = __builtin_bit_cast(s16x8, g2h[((c * 2 + mt) * 2 + ks) * 64 + lane]);
            a2l[mt][ks] = __builtin_bit_cast(s16x8, g2l[((c * 2 + mt) * 2 + ks) * 64 + lane]);
        }
    f32x4 b2v[2];
    {
        const f32x4* p2 = (const f32x4*)(gen_b2 + (size_t)c * 32);
        #pragma unroll
        for (int mt = 0; mt < 2; ++mt) b2v[mt] = p2[4 * mt + q];
    }

    for (int it = 0; it < 16; ++it) {
        const int bg = base + it * 16 + bl;
        const size_t ab = ((size_t)c * NB + bg) * 8;

        // B-frags: lane (q,bl) holds act[k = 32*ks2 + 8q + j] of batch bg
        s16x8 bh0 = __builtin_bit_cast(s16x8, actHI[ab + q]);
        s16x8 bl0 = __builtin_bit_cast(s16x8, actLO[ab + q]);
        s16x8 bh1 = __builtin_bit_cast(s16x8, actHI[ab + 4 + q]);
        s16x8 bl1 = __builtin_bit_cast(s16x8, actLO[ab + 4 + q]);

        f32x4 d0 = {0.f,0.f,0.f,0.f}, d1 = {0.f,0.f,0.f,0.f};
        // ks2 = 0 (split-3)
        d0 = mfma16(a2h[0][0], bh0, d0);
        d0 = mfma16(a2h[0][0], bl0, d0);
        d0 = mfma16(a2l[0][0], bh0, d0);
        d1 = mfma16(a2h[1][0], bh0, d1);
        d1 = mfma16(a2h[1][0], bl0, d1);
        d1 = mfma16(a2l[1][0], bh0, d1);
        // ks2 = 1
        d0 = mfma16(a2h[0][1], bh1, d0);
        d0 = mfma16(a2h[0][1], bl1, d0);
        d0 = mfma16(a2l[0][1], bh1, d0);
        d1 = mfma16(a2h[1][1], bh1, d1);
        d1 = mfma16(a2h[1][1], bl1, d1);
        d1 = mfma16(a2l[1][1], bh1, d1);

        d0 += b2v[0];
        d1 += b2v[1];

        // l2norm over 32 d's (colC-proven shfl reduction)
        float ss = 0.f;
        #pragma unroll
        for (int r = 0; r < 4; ++r) { ss = fmaf(d0[r], d0[r], ss); ss = fmaf(d1[r], d1[r], ss); }
        ss += __shfl_xor(ss, 16);
        ss += __shfl_xor(ss, 32);
        const float inv = 1.f / fmaxf(sqrtf(ss), 1e-12f);

        // tn fp32 store: d = 16*mt + 4q + r at plane (c*32+d)*NB + bg
        #pragma unroll
        for (int r = 0; r < 4; ++r)
            tn_ws[((size_t)(c * 32 + 4 * q + r)) * NB + bg] = d0[r] * inv;
        #pragma unroll
        for (int r = 0; r < 4; ++r)
            tn_ws[((size_t)(c * 32 + 16 + 4 * q + r)) * NB + bg] = d1[r] * inv;
    }
}

// ============ Kernel B1: scalar trace pack + fp32 gate partials (proven; gate MUST stay fp32) ============
__global__ __launch_bounds__(256, 4)
void colB1(const float* __restrict__ tn_ws, const float* __restrict__ g_W,
           uint4* __restrict__ trHI, uint4* __restrict__ trLO,
           float* __restrict__ part)
{
    const int c = blockIdx.x >> 8;
    const int b = ((blockIdx.x & 255) << 8) + threadIdx.x;

    float tn[32];
    #pragma unroll
    for (int d = 0; d < 32; ++d) tn[d] = tn_ws[((size_t)(c * 32 + d)) * NB + b];

    // ---- packed bf16 hi/lo trace store (R2 verbatim) ----
    {
        const size_t base = ((size_t)c * NB + b) * 4;
        #pragma unroll
        for (int k = 0; k < 4; ++k) {
            unsigned hw[4], lw[4];
            #pragma unroll
            for (int i = 0; i < 4; ++i) {
                const int e = 8 * k + 2 * i;
                unsigned h0 = bfrnd(tn[e]),   h1 = bfrnd(tn[e+1]);
                float r0 = tn[e]   - bfval(h0);
                float r1 = tn[e+1] - bfval(h1);
                hw[i] = h0 | (h1 << 16);
                lw[i] = bfrnd(r0) | (bfrnd(r1) << 16);
            }
            uint4 u; u.x = hw[0]; u.y = hw[1]; u.z = hw[2]; u.w = hw[3];
            trHI[base + k] = u;
            uint4 v; v.x = lw[0]; v.y = lw[1]; v.z = lw[2]; v.w = lw[3];
            trLO[base + k] = v;
        }
    }
    // ---- gate partials fp32 (flip-hazard analysis: ~4 expected bf16 flips/run -> fp32 mandatory) ----
    {
        float p[7] = {0.f,0.f,0.f,0.f,0.f,0.f,0.f};
        for (int k = 0; k < 32; ++k) {
            const float v = tn[k];
            const float* w = g_W + (c * 32 + k) * 7;
            #pragma unroll
            for (int l2 = 0; l2 < 7; ++l2) p[l2] = fmaf(v, w[l2], p[l2]);
        }
        #pragma unroll
        for (int l2 = 0; l2 < 7; ++l2) part[((size_t)(c * 7 + l2)) * NB + b] = p[l2];
    }
}

// ============ Kernel B2: gates + comp_conf output (R2 verbatim) ============
__global__ __launch_bounds__(256, 4)
void colB2(const float* __restrict__ g_b,
           const float* __restrict__ part, const float* __restrict__ conf,
           float* __restrict__ gates, float* __restrict__ out2)
{
    const int b = blockIdx.x * 256 + threadIdx.x;

    float g[7];
    #pragma unroll
    for (int l = 0; l < 7; ++l) g[l] = g_b[l];
    for (int c = 0; c < 7; ++c) {
        #pragma unroll
        for (int l = 0; l < 7; ++l) g[l] += part[((size_t)(c * 7 + l)) * NB + b];
    }
    #pragma unroll
    for (int l = 0; l < 7; ++l) {
        g[l] = sigf(g[l]);
        gates[(size_t)l * NB + b] = g[l];
    }

    float cf[7];
    #pragma unroll
    for (int c = 0; c < 7; ++c) cf[c] = conf[(size_t)c * NB + b];

    float* op = out2 + (size_t)b * 21;
    #pragma unroll
    for (int t = 0; t < 21; ++t) {
        const int l = t / 3;
        const float gl = g[l];
        op[t] = (gl >= 0.3f) ? cf[T_SRC[t]] * cf[T_PAR[t]] * gl : 0.f;
    }
}

// ============ Kernel C: composers via split-bf16 MFMA (unchanged, proven) ============
__global__ __launch_bounds__(256, 2)
void colC(const uint4* __restrict__ trHI, const uint4* __restrict__ trLO,
          const float* __restrict__ gates,
          const uint4* __restrict__ w1fh, const uint4* __restrict__ w1fl,
          const uint4* __restrict__ w2fh, const uint4* __restrict__ w2fl,
          const float* __restrict__ c_b1,
          const float* __restrict__ c_g,  const float* __restrict__ c_be,
          const float* __restrict__ c_b2, float* __restrict__ out)
{
    __shared__ float lds[4][16 * 68];   // per-wave CH^T buffer [b][j], stride 68 (pad)

    const int wave = threadIdx.x >> 6;
    const int lane = threadIdx.x & 63;
    const int q    = lane >> 4;         // quad
    const int bl   = lane & 15;         // batch-in-tile (MFMA column)

    const int t   = blockIdx.x >> 6;    // 64 blocks per task
    const int l   = t / 3;
    const int src = T_SRC[t];
    const int par = T_PAR[t];
    const int base = ((blockIdx.x & 63) << 10) + (wave << 8);   // wave's batch base

    s16x8 w1h[4][2], w1l[4][2], w2h[2][2], w2l[2][2];
    #pragma unroll
    for (int mt = 0; mt < 4; ++mt)
        #pragma unroll
        for (int ks = 0; ks < 2; ++ks) {
            w1h[mt][ks] = __builtin_bit_cast(s16x8, w1fh[((l * 4 + mt) * 2 + ks) * 64 + lane]);
            w1l[mt][ks] = __builtin_bit_cast(s16x8, w1fl[((l * 4 + mt) * 2 + ks) * 64 + lane]);
        }
    #pragma unroll
    for (int mt = 0; mt < 2; ++mt)
        #pragma unroll
        for (int ks = 0; ks < 2; ++ks) {
            w2h[mt][ks] = __builtin_bit_cast(s16x8, w2fh[((l * 2 + mt) * 2 + ks) * 64 + lane]);
            w2l[mt][ks] = __builtin_bit_cast(s16x8, w2fl[((l * 2 + mt) * 2 + ks) * 64 + lane]);
        }

    f32x4 b1v[4], gv[4], bev[4], b2v[2];
    {
        const f32x4* p1 = (const f32x4*)(c_b1 + (size_t)l * 64);
        const f32x4* pg = (const f32x4*)(c_g  + (size_t)l * 64);
        const f32x4* pb = (const f32x4*)(c_be + (size_t)l * 64);
        #pragma unroll
        for (int mt = 0; mt < 4; ++mt) {
            b1v[mt] = p1[4 * mt + q]; gv[mt] = pg[4 * mt + q]; bev[mt] = pb[4 * mt + q];
        }
        const f32x4* p2 = (const f32x4*)(c_b2 + (size_t)l * 32);
        #pragma unroll
        for (int mt = 0; mt < 2; ++mt) b2v[mt] = p2[4 * mt + q];
    }

    float* ldsw = &lds[wave][0];

    for (int it = 0; it < 16; ++it) {
        const int bg = base + it * 16 + bl;

        const size_t sb = ((size_t)src * NB + bg) * 4 + q;
        const size_t pb = ((size_t)par * NB + bg) * 4 + q;
        s16x8 bsh = __builtin_bit_cast(s16x8, trHI[sb]);
        s16x8 bsl = __builtin_bit_cast(s16x8, trLO[sb]);
        s16x8 bph = __builtin_bit_cast(s16x8, trHI[pb]);
        s16x8 bpl = __builtin_bit_cast(s16x8, trLO[pb]);
        const float gate = gates[(size_t)l * NB + bg];

        f32x4 acc[4];
        #pragma unroll
        for (int mt = 0; mt < 4; ++mt) {
            f32x4 a = {0.f, 0.f, 0.f, 0.f};
            a = mfma16(w1h[mt][0], bsh, a);
            a = mfma16(w1h[mt][0], bsl, a);
            a = mfma16(w1l[mt][0], bsh, a);
            a = mfma16(w1h[mt][1], bph, a);
            a = mfma16(w1h[mt][1], bpl, a);
            a = mfma16(w1l[mt][1], bph, a);
            acc[mt] = a;
        }
        #pragma unroll
        for (int mt = 0; mt < 4; ++mt) acc[mt] += b1v[mt];

        float s = 0.f;
        #pragma unroll
        for (int mt = 0; mt < 4; ++mt)
            #pragma unroll
            for (int r = 0; r < 4; ++r) s += acc[mt][r];
        s += __shfl_xor(s, 16);
        s += __shfl_xor(s, 32);
        const float mean = s * (1.f / 64.f);
        float v = 0.f;
        #pragma unroll
        for (int mt = 0; mt < 4; ++mt)
            #pragma unroll
            for (int r = 0; r < 4; ++r) { float d = acc[mt][r] - mean; v = fmaf(d, d, v); }
        v += __shfl_xor(v, 16);
        v += __shfl_xor(v, 32);
        const float rs = 1.f / sqrtf(v * (1.f / 64.f) + 1e-5f);

        #pragma unroll
        for (int mt = 0; mt < 4; ++mt) {
            f32x4 x;
            #pragma unroll
            for (int r = 0; r < 4; ++r)
                x[r] = fmaxf(fmaf((acc[mt][r] - mean) * rs, gv[mt][r], bev[mt][r]), 0.f);
            *(f32x4*)&ldsw[bl * 68 + 16 * mt + 4 * q] = x;
        }

        f32x4 d0 = {0.f,0.f,0.f,0.f}, d1 = {0.f,0.f,0.f,0.f};
        #pragma unroll
        for (int ks2 = 0; ks2 < 2; ++ks2) {
            f32x4 c0 = *(const f32x4*)&ldsw[bl * 68 + 32 * ks2 + 8 * q];
            f32x4 c1 = *(const f32x4*)&ldsw[bl * 68 + 32 * ks2 + 8 * q + 4];
            float vv[8] = {c0[0], c0[1], c0[2], c0[3], c1[0], c1[1], c1[2], c1[3]};
            s16x8 chh, chl; pack8(vv, chh, chl);
            d0 = mfma16(w2h[0][ks2], chh, d0);
            d0 = mfma16(w2h[0][ks2], chl, d0);
            d0 = mfma16(w2l[0][ks2], chh, d0);
            d1 = mfma16(w2h[1][ks2], chh, d1);
            d1 = mfma16(w2h[1][ks2], chl, d1);
            d1 = mfma16(w2l[1][ks2], chh, d1);
        }
        d0 += b2v[0];
        d1 += b2v[1];

        float ss = 0.f;
        #pragma unroll
        for (int r = 0; r < 4; ++r) { ss = fmaf(d0[r], d0[r], ss); ss = fmaf(d1[r], d1[r], ss); }
        ss += __shfl_xor(ss, 16);
        ss += __shfl_xor(ss, 32);
        const float inv   = 1.f / fmaxf(sqrtf(ss), 1e-12f);
        const float scale = (gate >= 0.3f) ? gate * inv : 0.f;

        float* op = out + (size_t)bg * 672 + t * 32;
        f32x4 o0, o1;
        #pragma unroll
        for (int r = 0; r < 4; ++r) { o0[r] = d0[r] * scale; o1[r] = d1[r] * scale; }
        *(f32x4*)(op + 4 * q)      = o0;
        *(f32x4*)(op + 16 + 4 * q) = o1;
    }
}

extern "C" void kernel_launch(void* const* d_in, const int* in_sizes, int n_in,
                              void* d_out, int out_size, void* d_ws, size_t ws_size,
                              hipStream_t stream) {
    const float* z      = (const float*)d_in[0];
    const float* gen_W1 = (const float*)d_in[1];
    const float* gen_b1 = (const float*)d_in[2];
    const float* gen_g  = (const float*)d_in[3];
    const float* gen_be = (const float*)d_in[4];
    const float* gen_W2 = (const float*)d_in[5];
    const float* gen_b2 = (const float*)d_in[6];
    const float* cf_W1  = (const float*)d_in[7];
    const float* cf_b1  = (const float*)d_in[8];
    const float* cf_W2  = (const float*)d_in[9];
    const float* cf_b2  = (const float*)d_in[10];
    const float* g_W    = (const float*)d_in[11];
    const float* g_b    = (const float*)d_in[12];
    const float* c_W1   = (const float*)d_in[13];
    const float* c_b1   = (const float*)d_in[14];
    const float* c_g    = (const float*)d_in[15];
    const float* c_be   = (const float*)d_in[16];
    const float* c_W2   = (const float*)d_in[17];
    const float* c_b2   = (const float*)d_in[18];

    char* wsb = (char*)d_ws;
    uint4* trHI  = (uint4*)(wsb + OFF_TRHI);
    uint4* trLO  = (uint4*)(wsb + OFF_TRLO);
    float* conf  = (float*)(wsb + OFF_CONF);
    float* part  = (float*)(wsb + OFF_PART);
    float* gates = (float*)(wsb + OFF_GATE);
    uint4* w1fh  = (uint4*)(wsb + OFF_W1H);
    uint4* w1fl  = (uint4*)(wsb + OFF_W1L);
    uint4* w2fh  = (uint4*)(wsb + OFF_W2H);
    uint4* w2fl  = (uint4*)(wsb + OFF_W2L);
    uint4* g2h   = (uint4*)(wsb + OFF_G2H);
    uint4* g2l   = (uint4*)(wsb + OFF_G2L);

    float* outp = (float*)d_out;
    float* out2 = outp + (size_t)NB * 672;

    // d_out scratch overlay (consumed before colC overwrites the composed region)
    uint4* actHI = (uint4*)outp;                          // 58,720,256 B
    uint4* actLO = actHI + (size_t)7 * NB * 8;            // 58,720,256 B
    float* tn_ws = outp + (size_t)29360128;               // 58,720,256 B, ends at NB*672*4

    colP<<<dim3(28), dim3(256), 0, stream>>>(
        c_W1, c_W2, gen_W2, w1fh, w1fl, w2fh, w2fl, g2h, g2l);
    colA1<<<dim3(7 * 256), dim3(256), 0, stream>>>(
        z, gen_W1, gen_b1, gen_g, gen_be, cf_W1, cf_b1, cf_W2, cf_b2,
        actHI, actLO, conf);
    colA2<<<dim3(7 * 64), dim3(256), 0, stream>>>(
        actHI, actLO, g2h, g2l, gen_b2, tn_ws);
    colB1<<<dim3(7 * 256), dim3(256), 0, stream>>>(
        tn_ws, g_W, trHI, trLO, part);
    colB2<<<dim3(256), dim3(256), 0, stream>>>(g_b, part, conf, gates, out2);
    colC<<<dim3(21 * 64), dim3(256), 0, stream>>>(
        trHI, trLO, gates, w1fh, w1fl, w2fh, w2fl,
        c_b1, c_g, c_be, c_b2, outp);
}

// Round 9
// 448.520 us; speedup vs baseline: 1.1667x; 1.0823x over previous
//
#include <hip/hip_runtime.h>
#include <math.h>

#define NB 65536

typedef short s16x8 __attribute__((ext_vector_type(8)));
typedef float f32x4 __attribute__((ext_vector_type(4)));

// ---------------- workspace layout (bytes) ----------------
#define SZ_TR     ((size_t)7*NB*32*2)            // packed bf16 traces (hi or lo)
#define OFF_TRHI  ((size_t)0)
#define OFF_TRLO  (OFF_TRHI + SZ_TR)
#define OFF_CONF  (OFF_TRLO + SZ_TR)
#define SZ_CONF   ((size_t)7*NB*4)
#define OFF_PART  (OFF_CONF + SZ_CONF)
#define SZ_PART   ((size_t)49*NB*4)
#define OFF_GATE  (OFF_PART + SZ_PART)
#define SZ_GATE   ((size_t)7*NB*4)
#define OFF_W1H   (OFF_GATE + SZ_GATE)           // composer W1 frags
#define SZ_W1F    ((size_t)7*4*2*64*16)
#define OFF_W1L   (OFF_W1H + SZ_W1F)
#define OFF_W2H   (OFF_W1L + SZ_W1F)
#define SZ_W2F    ((size_t)7*2*2*64*16)
#define OFF_W2L   (OFF_W2H + SZ_W2F)
#define OFF_G2H   (OFF_W2L + SZ_W2F)             // gen_W2 frags [7][2][2][64]u4
#define SZ_G2     ((size_t)7*2*2*64*16)
#define OFF_G2L   (OFF_G2H + SZ_G2)
// total ~75.5 MB
//
// d_out scratch overlay (consumed before colC overwrites the composed region):
//   actHI : uint4, PLANE-MAJOR [c*8+chunk][b]  at outp byte 0   (58,720,256 B)
//   actLO : same                               at byte 58,720,256
//   tn    : float [c*32+d][b]                  at byte 117,440,512 (58,720,256 B)
//   => ends at 176,160,768 = NB*672*4 exactly (composed region)
//
// NOTE (R8 lesson): per-wave LDS transpose of the tn MFMA output is empirically
// broken (R3: 0.497, R8: 0.743) despite matching colC's geometry on paper.
// Keep tn on the fp32 memory round-trip (R6/R7-proven) until a no-LDS fusion
// is validated in isolation.

// task t = l*3+p; src = FANO[l][p], par = FANO[l][(p+1)%3]
static __device__ const int T_SRC[21] = {0,1,2, 0,3,4, 0,5,6, 1,3,5, 1,4,6, 2,3,6, 2,4,5};
static __device__ const int T_PAR[21] = {1,2,0, 3,4,0, 5,6,0, 3,5,1, 4,6,1, 3,6,2, 4,5,2};

__device__ __forceinline__ float sigf(float x) { return 1.f / (1.f + expf(-x)); }

// round-to-nearest-even f32 -> bf16 (as uint16 in low bits)
__device__ __forceinline__ unsigned bfrnd(float x) {
    unsigned u = __builtin_bit_cast(unsigned, x);
    return (u + 0x7FFFu + ((u >> 16) & 1u)) >> 16;
}
__device__ __forceinline__ float bfval(unsigned h) {
    return __builtin_bit_cast(float, h << 16);
}

__device__ __forceinline__ f32x4 mfma16(s16x8 a, s16x8 b, f32x4 c) {
    return __builtin_amdgcn_mfma_f32_16x16x32_bf16(a, b, c, 0, 0, 0);
}

// pack 8 floats -> hi frag + lo frag (bf16 split)
__device__ __forceinline__ void pack8(const float* v, s16x8& hi, s16x8& lo) {
    uint4 hu, lu;
    unsigned h[8], l[8];
    #pragma unroll
    for (int i = 0; i < 8; ++i) {
        h[i] = bfrnd(v[i]);
        float rem = v[i] - bfval(h[i]);
        l[i] = bfrnd(rem);
    }
    hu.x = h[0] | (h[1] << 16); hu.y = h[2] | (h[3] << 16);
    hu.z = h[4] | (h[5] << 16); hu.w = h[6] | (h[7] << 16);
    lu.x = l[0] | (l[1] << 16); lu.y = l[2] | (l[3] << 16);
    lu.z = l[4] | (l[5] << 16); lu.w = l[6] | (l[7] << 16);
    hi = __builtin_bit_cast(s16x8, hu);
    lo = __builtin_bit_cast(s16x8, lu);
}

// colony-specific activation applied in-place to N values (exact lib funcs, proven)
template <int N>
__device__ __forceinline__ void actN(int c, float* a) {
    switch (c) {
        case 0:
            #pragma unroll
            for (int u = 0; u < N; ++u) a[u] = fmaxf(a[u], 0.f);
            break;
        case 1:
            #pragma unroll
            for (int u = 0; u < N; ++u) a[u] = tanhf(a[u]);
            break;
        case 2:
            #pragma unroll
            for (int u = 0; u < N; ++u) a[u] = 0.5f * a[u] * (1.f + erff(a[u] * 0.70710678118654752f));
            break;
        case 3:
            #pragma unroll
            for (int u = 0; u < N; ++u) a[u] = a[u] * sigf(a[u]);
            break;
        case 4:
            #pragma unroll
            for (int u = 0; u < N; ++u) a[u] = fmaxf(a[u], 0.f) + log1pf(expf(-fabsf(a[u])));
            break;
        case 5:
            #pragma unroll
            for (int u = 0; u < N; ++u) a[u] = sigf(a[u]);
            break;
        default:
            #pragma unroll
            for (int u = 0; u < N; ++u) a[u] = fminf(fmaxf(a[u], -1.f), 1.f);
            break;
    }
}

// ============ Kernel P: prepack MFMA A-fragments (composer W1/W2 + gen_W2) ============
__global__ __launch_bounds__(256, 4)
void colP(const float* __restrict__ c_W1, const float* __restrict__ c_W2,
          const float* __restrict__ gen_W2,
          uint4* __restrict__ w1h, uint4* __restrict__ w1l,
          uint4* __restrict__ w2h, uint4* __restrict__ w2l,
          uint4* __restrict__ g2h, uint4* __restrict__ g2l)
{
    const int e = blockIdx.x * 256 + threadIdx.x;
    if (e < 3584) {                       // composer W1 frags
        const int lane = e & 63, er = e >> 6;
        const int ks = er & 1, mt = (er >> 1) & 3, l = er >> 3;
        const int j  = mt * 16 + (lane & 15);
        const int k0 = ks * 32 + (lane >> 4) * 8;
        float v[8];
        #pragma unroll
        for (int jj = 0; jj < 8; ++jj) v[jj] = c_W1[((size_t)(l * 64 + k0 + jj)) * 64 + j];
        s16x8 hi, lo; pack8(v, hi, lo);
        w1h[e] = __builtin_bit_cast(uint4, hi);
        w1l[e] = __builtin_bit_cast(uint4, lo);
    } else if (e < 5376) {                // composer W2 frags
        const int e2 = e - 3584;
        const int lane = e2 & 63, er = e2 >> 6;
        const int ks2 = er & 1, mt2 = (er >> 1) & 1, l = er >> 2;
        const int d  = mt2 * 16 + (lane & 15);
        const int k0 = ks2 * 32 + (lane >> 4) * 8;
        float v[8];
        #pragma unroll
        for (int jj = 0; jj < 8; ++jj) v[jj] = c_W2[((size_t)(l * 64 + k0 + jj)) * 32 + d];
        s16x8 hi, lo; pack8(v, hi, lo);
        w2h[e2] = __builtin_bit_cast(uint4, hi);
        w2l[e2] = __builtin_bit_cast(uint4, lo);
    } else if (e < 7168) {                // gen_W2 frags (same transform, same shape)
        const int e2 = e - 5376;
        const int lane = e2 & 63, er = e2 >> 6;
        const int ks2 = er & 1, mt2 = (er >> 1) & 1, c = er >> 2;
        const int d  = mt2 * 16 + (lane & 15);
        const int k0 = ks2 * 32 + (lane >> 4) * 8;
        float v[8];
        #pragma unroll
        for (int jj = 0; jj < 8; ++jj) v[jj] = gen_W2[((size_t)(c * 64 + k0 + jj)) * 32 + d];
        s16x8 hi, lo; pack8(v, hi, lo);
        g2h[e2] = __builtin_bit_cast(uint4, hi);
        g2l[e2] = __builtin_bit_cast(uint4, lo);
    }
}

// ============ Kernel A1: scalar conf + gen1 + LN + act, TWO-PASS (R7-proven) ============
// R9 single change: act stores PLANE-MAJOR act[(c*8+chunk)*NB + b]. R7's thread-major
// layout made every store hit 64 lines at 1/8 fill (128-B lane stride) -> partial-line
// evictions inflated WRITE_SIZE to 218 MB vs 119 ideal.
__global__ __launch_bounds__(256, 4)
void colA1(const float* __restrict__ z,
           const float* __restrict__ gen_W1, const float* __restrict__ gen_b1,
           const float* __restrict__ gen_g,  const float* __restrict__ gen_be,
           const float* __restrict__ cf_W1,  const float* __restrict__ cf_b1,
           const float* __restrict__ cf_W2,  const float* __restrict__ cf_b2,
           uint4* __restrict__ actHI, uint4* __restrict__ actLO,
           float* __restrict__ conf)
{
    const int c = blockIdx.x >> 8;
    const int b = ((blockIdx.x & 255) << 8) + threadIdx.x;

    float zv[14];
    {
        const float* zp = z + ((size_t)b * 7 + (size_t)c) * 14;
        #pragma unroll
        for (int i = 0; i < 7; ++i) {
            float2 u = *(const float2*)(zp + 2 * i);
            zv[2*i] = u.x; zv[2*i+1] = u.y;
        }
    }

    // ---- confidence head (proven) ----
    {
        float hc[32];
        const float* bp = cf_b1 + c * 32;
        #pragma unroll
        for (int k = 0; k < 32; ++k) hc[k] = bp[k];
        const float* W = cf_W1 + c * 14 * 32;
        for (int i = 0; i < 14; ++i) {
            const float zi = zv[i];
            const float* w = W + i * 32;
            #pragma unroll
            for (int k = 0; k < 32; ++k) hc[k] = fmaf(zi, w[k], hc[k]);
        }
        float cl = cf_b2[c];
        const float* w2 = cf_W2 + c * 32;
        #pragma unroll
        for (int k = 0; k < 32; ++k) cl = fmaf(fmaxf(hc[k], 0.f), w2[k], cl);
        conf[(size_t)c * NB + b] = sigf(cl);
    }

    const float* W1p = gen_W1 + c * 14 * 64;
    const float* b1p = gen_b1 + c * 64;

    // ---- pass 1: LN statistics (chunked h, only sum/sumsq live across chunks) ----
    float sum = 0.f, ssq = 0.f;
    #pragma unroll 1
    for (int j0 = 0; j0 < 64; j0 += 16) {
        float hj[16];
        #pragma unroll
        for (int u = 0; u < 16; ++u) hj[u] = b1p[j0 + u];
        #pragma unroll
        for (int i = 0; i < 14; ++i) {
            const float zi = zv[i];
            const float* w = W1p + i * 64 + j0;
            #pragma unroll
            for (int u = 0; u < 16; ++u) hj[u] = fmaf(zi, w[u], hj[u]);
        }
        #pragma unroll
        for (int u = 0; u < 16; ++u) { sum += hj[u]; ssq = fmaf(hj[u], hj[u], ssq); }
    }
    const float mean = sum * (1.f / 64.f);
    const float var  = fmaxf(ssq * (1.f / 64.f) - mean * mean, 0.f);
    const float rs   = 1.f / sqrtf(var + 1e-5f);

    // opaque fence: make pass-2 recompute non-CSE-able against pass 1 (proven)
    #pragma unroll
    for (int i = 0; i < 14; ++i) asm volatile("" : "+v"(zv[i]));

    // ---- pass 2: recompute chunk-wise, LN + act, pack to PLANE-MAJOR act chunks ----
    {
        const float* gp  = gen_g  + c * 64;
        const float* bep = gen_be + c * 64;
        #pragma unroll 1
        for (int j0 = 0; j0 < 64; j0 += 16) {
            float a16[16];
            #pragma unroll
            for (int u = 0; u < 16; ++u) a16[u] = b1p[j0 + u];
            #pragma unroll
            for (int i = 0; i < 14; ++i) {
                const float zi = zv[i];
                const float* w = W1p + i * 64 + j0;
                #pragma unroll
                for (int u = 0; u < 16; ++u) a16[u] = fmaf(zi, w[u], a16[u]);
            }
            #pragma unroll
            for (int u = 0; u < 16; ++u)
                a16[u] = fmaf((a16[u] - mean) * rs, gp[j0 + u], bep[j0 + u]);
            actN<16>(c, a16);
            // pack two 8-chunks; chunk k covers act[8k..8k+7]; store plane-major
            #pragma unroll
            for (int half = 0; half < 2; ++half) {
                unsigned hw[4], lw[4];
                #pragma unroll
                for (int i = 0; i < 4; ++i) {
                    const int e = half * 8 + 2 * i;
                    unsigned h0 = bfrnd(a16[e]), h1 = bfrnd(a16[e+1]);
                    float r0 = a16[e]   - bfval(h0);
                    float r1 = a16[e+1] - bfval(h1);
                    hw[i] = h0 | (h1 << 16);
                    lw[i] = bfrnd(r0) | (bfrnd(r1) << 16);
                }
                const int k = (j0 >> 3) + half;
                uint4 u4; u4.x = hw[0]; u4.y = hw[1]; u4.z = hw[2]; u4.w = hw[3];
                actHI[((size_t)(c * 8 + k)) * NB + b] = u4;
                uint4 v4; v4.x = lw[0]; v4.y = lw[1]; v4.z = lw[2]; v4.w = lw[3];
                actLO[((size_t)(c * 8 + k)) * NB + b] = v4;
            }
        }
    }
}

// ============ Kernel A2: gen2 via MFMA (R6/R7-proven; plane-major loads only change) ============
// B-frags loaded straight from act chunks. No LDS. Output tn stored fp32 in
// [c][d][b] planes (coalesced across b).
__global__ __launch_bounds__(256, 4)
void colA2(const uint4* __restrict__ actHI, const uint4* __restrict__ actLO,
           const uint4* __restrict__ g2h, const uint4* __restrict__ g2l,
           const float* __restrict__ gen_b2,
           float* __restrict__ tn_ws)
{
    const int wave = threadIdx.x >> 6;
    const int lane = threadIdx.x & 63;
    const int q    = lane >> 4;
    const int bl   = lane & 15;
    const int c    = blockIdx.x >> 6;                       // 7*64 blocks
    const int base = ((blockIdx.x & 63) << 10) + (wave << 8);

    s16x8 a2h[2][2], a2l[2][2];
    #pragma unroll
    for (int mt = 0; mt < 2; ++mt)
        #pragma unroll
        for (int ks = 0; ks < 2; ++ks) {
            a2h[mt][ks] = __builtin_bit_cast(s16x8, g2h[((c * 2 + mt) * 2 + ks) * 64 + lane]);
            a2l[mt][ks] = __builtin_bit_cast(s16x8, g2l[((c * 2 + mt) * 2 + ks) * 64 + lane]);
        }
    f32x4 b2v[2];
    {
        const f32x4* p2 = (const f32x4*)(gen_b2 + (size_t)c * 32);
        #pragma unroll
        for (int mt = 0; mt < 2; ++mt) b2v[mt] = p2[4 * mt + q];
    }

    for (int it = 0; it < 16; ++it) {
        const int bg = base + it * 16 + bl;

        // plane-major act loads: lane (q,bl) holds act[k = 32*ks2 + 8q + j] of batch bg
        s16x8 bh0 = __builtin_bit_cast(s16x8, actHI[((size_t)(c * 8 + q)) * NB + bg]);
        s16x8 bl0 = __builtin_bit_cast(s16x8, actLO[((size_t)(c * 8 + q)) * NB + bg]);
        s16x8 bh1 = __builtin_bit_cast(s16x8, actHI[((size_t)(c * 8 + 4 + q)) * NB + bg]);
        s16x8 bl1 = __builtin_bit_cast(s16x8, actLO[((size_t)(c * 8 + 4 + q)) * NB + bg]);

        f32x4 d0 = {0.f,0.f,0.f,0.f}, d1 = {0.f,0.f,0.f,0.f};
        // ks2 = 0 (split-3, R6-proven)
        d0 = mfma16(a2h[0][0], bh0, d0);
        d0 = mfma16(a2h[0][0], bl0, d0);
        d0 = mfma16(a2l[0][0], bh0, d0);
        d1 = mfma16(a2h[1][0], bh0, d1);
        d1 = mfma16(a2h[1][0], bl0, d1);
        d1 = mfma16(a2l[1][0], bh0, d1);
        // ks2 = 1
        d0 = mfma16(a2h[0][1], bh1, d0);
        d0 = mfma16(a2h[0][1], bl1, d0);
        d0 = mfma16(a2l[0][1], bh1, d0);
        d1 = mfma16(a2h[1][1], bh1, d1);
        d1 = mfma16(a2h[1][1], bl1, d1);
        d1 = mfma16(a2l[1][1], bh1, d1);

        d0 += b2v[0];
        d1 += b2v[1];

        // l2norm over 32 d's (proven shfl reduction)
        float ss = 0.f;
        #pragma unroll
        for (int r = 0; r < 4; ++r) { ss = fmaf(d0[r], d0[r], ss); ss = fmaf(d1[r], d1[r], ss); }
        ss += __shfl_xor(ss, 16);
        ss += __shfl_xor(ss, 32);
        const float inv = 1.f / fmaxf(sqrtf(ss), 1e-12f);

        // tn fp32 store: d = 16*mt + 4q + r at plane (c*32+d)*NB + bg
        #pragma unroll
        for (int r = 0; r < 4; ++r)
            tn_ws[((size_t)(c * 32 + 4 * q + r)) * NB + bg] = d0[r] * inv;
        #pragma unroll
        for (int r = 0; r < 4; ++r)
            tn_ws[((size_t)(c * 32 + 16 + 4 * q + r)) * NB + bg] = d1[r] * inv;
    }
}

// ============ Kernel B1: scalar trace pack + fp32 gate partials (proven; gate MUST stay fp32) ============
__global__ __launch_bounds__(256, 4)
void colB1(const float* __restrict__ tn_ws, const float* __restrict__ g_W,
           uint4* __restrict__ trHI, uint4* __restrict__ trLO,
           float* __restrict__ part)
{
    const int c = blockIdx.x >> 8;
    const int b = ((blockIdx.x & 255) << 8) + threadIdx.x;

    float tn[32];
    #pragma unroll
    for (int d = 0; d < 32; ++d) tn[d] = tn_ws[((size_t)(c * 32 + d)) * NB + b];

    // ---- packed bf16 hi/lo trace store (proven) ----
    {
        const size_t base = ((size_t)c * NB + b) * 4;
        #pragma unroll
        for (int k = 0; k < 4; ++k) {
            unsigned hw[4], lw[4];
            #pragma unroll
            for (int i = 0; i < 4; ++i) {
                const int e = 8 * k + 2 * i;
                unsigned h0 = bfrnd(tn[e]),   h1 = bfrnd(tn[e+1]);
                float r0 = tn[e]   - bfval(h0);
                float r1 = tn[e+1] - bfval(h1);
                hw[i] = h0 | (h1 << 16);
                lw[i] = bfrnd(r0) | (bfrnd(r1) << 16);
            }
            uint4 u; u.x = hw[0]; u.y = hw[1]; u.z = hw[2]; u.w = hw[3];
            trHI[base + k] = u;
            uint4 v; v.x = lw[0]; v.y = lw[1]; v.z = lw[2]; v.w = lw[3];
            trLO[base + k] = v;
        }
    }
    // ---- gate partials fp32 (flip-hazard: gate logits never leave fp32) ----
    {
        float p[7] = {0.f,0.f,0.f,0.f,0.f,0.f,0.f};
        for (int k = 0; k < 32; ++k) {
            const float v = tn[k];
            const float* w = g_W + (c * 32 + k) * 7;
            #pragma unroll
            for (int l2 = 0; l2 < 7; ++l2) p[l2] = fmaf(v, w[l2], p[l2]);
        }
        #pragma unroll
        for (int l2 = 0; l2 < 7; ++l2) part[((size_t)(c * 7 + l2)) * NB + b] = p[l2];
    }
}

// ============ Kernel B2: gates + comp_conf output (proven) ============
__global__ __launch_bounds__(256, 4)
void colB2(const float* __restrict__ g_b,
           const float* __restrict__ part, const float* __restrict__ conf,
           float* __restrict__ gates, float* __restrict__ out2)
{
    const int b = blockIdx.x * 256 + threadIdx.x;

    float g[7];
    #pragma unroll
    for (int l = 0; l < 7; ++l) g[l] = g_b[l];
    for (int c = 0; c < 7; ++c) {
        #pragma unroll
        for (int l = 0; l < 7; ++l) g[l] += part[((size_t)(c * 7 + l)) * NB + b];
    }
    #pragma unroll
    for (int l = 0; l < 7; ++l) {
        g[l] = sigf(g[l]);
        gates[(size_t)l * NB + b] = g[l];
    }

    float cf[7];
    #pragma unroll
    for (int c = 0; c < 7; ++c) cf[c] = conf[(size_t)c * NB + b];

    float* op = out2 + (size_t)b * 21;
    #pragma unroll
    for (int t = 0; t < 21; ++t) {
        const int l = t / 3;
        const float gl = g[l];
        op[t] = (gl >= 0.3f) ? cf[T_SRC[t]] * cf[T_PAR[t]] * gl : 0.f;
    }
}

// ============ Kernel C: composers via split-bf16 MFMA (unchanged, proven) ============
__global__ __launch_bounds__(256, 2)
void colC(const uint4* __restrict__ trHI, const uint4* __restrict__ trLO,
          const float* __restrict__ gates,
          const uint4* __restrict__ w1fh, const uint4* __restrict__ w1fl,
          const uint4* __restrict__ w2fh, const uint4* __restrict__ w2fl,
          const float* __restrict__ c_b1,
          const float* __restrict__ c_g,  const float* __restrict__ c_be,
          const float* __restrict__ c_b2, float* __restrict__ out)
{
    __shared__ float lds[4][16 * 68];   // per-wave CH^T buffer [b][j], stride 68 (pad)

    const int wave = threadIdx.x >> 6;
    const int lane = threadIdx.x & 63;
    const int q    = lane >> 4;         // quad
    const int bl   = lane & 15;         // batch-in-tile (MFMA column)

    const int t   = blockIdx.x >> 6;    // 64 blocks per task
    const int l   = t / 3;
    const int src = T_SRC[t];
    const int par = T_PAR[t];
    const int base = ((blockIdx.x & 63) << 10) + (wave << 8);   // wave's batch base

    s16x8 w1h[4][2], w1l[4][2], w2h[2][2], w2l[2][2];
    #pragma unroll
    for (int mt = 0; mt < 4; ++mt)
        #pragma unroll
        for (int ks = 0; ks < 2; ++ks) {
            w1h[mt][ks] = __builtin_bit_cast(s16x8, w1fh[((l * 4 + mt) * 2 + ks) * 64 + lane]);
            w1l[mt][ks] = __builtin_bit_cast(s16x8, w1fl[((l * 4 + mt) * 2 + ks) * 64 + lane]);
        }
    #pragma unroll
    for (int mt = 0; mt < 2; ++mt)
        #pragma unroll
        for (int ks = 0; ks < 2; ++ks) {
            w2h[mt][ks] = __builtin_bit_cast(s16x8, w2fh[((l * 2 + mt) * 2 + ks) * 64 + lane]);
            w2l[mt][ks] = __builtin_bit_cast(s16x8, w2fl[((l * 2 + mt) * 2 + ks) * 64 + lane]);
        }

    f32x4 b1v[4], gv[4], bev[4], b2v[2];
    {
        const f32x4* p1 = (const f32x4*)(c_b1 + (size_t)l * 64);
        const f32x4* pg = (const f32x4*)(c_g  + (size_t)l * 64);
        const f32x4* pb = (const f32x4*)(c_be + (size_t)l * 64);
        #pragma unroll
        for (int mt = 0; mt < 4; ++mt) {
            b1v[mt] = p1[4 * mt + q]; gv[mt] = pg[4 * mt + q]; bev[mt] = pb[4 * mt + q];
        }
        const f32x4* p2 = (const f32x4*)(c_b2 + (size_t)l * 32);
        #pragma unroll
        for (int mt = 0; mt < 2; ++mt) b2v[mt] = p2[4 * mt + q];
    }

    float* ldsw = &lds[wave][0];

    for (int it = 0; it < 16; ++it) {
        const int bg = base + it * 16 + bl;

        const size_t sb = ((size_t)src * NB + bg) * 4 + q;
        const size_t pb = ((size_t)par * NB + bg) * 4 + q;
        s16x8 bsh = __builtin_bit_cast(s16x8, trHI[sb]);
        s16x8 bsl = __builtin_bit_cast(s16x8, trLO[sb]);
        s16x8 bph = __builtin_bit_cast(s16x8, trHI[pb]);
        s16x8 bpl = __builtin_bit_cast(s16x8, trLO[pb]);
        const float gate = gates[(size_t)l * NB + bg];

        f32x4 acc[4];
        #pragma unroll
        for (int mt = 0; mt < 4; ++mt) {
            f32x4 a = {0.f, 0.f, 0.f, 0.f};
            a = mfma16(w1h[mt][0], bsh, a);
            a = mfma16(w1h[mt][0], bsl, a);
            a = mfma16(w1l[mt][0], bsh, a);
            a = mfma16(w1h[mt][1], bph, a);
            a = mfma16(w1h[mt][1], bpl, a);
            a = mfma16(w1l[mt][1], bph, a);
            acc[mt] = a;
        }
        #pragma unroll
        for (int mt = 0; mt < 4; ++mt) acc[mt] += b1v[mt];

        float s = 0.f;
        #pragma unroll
        for (int mt = 0; mt < 4; ++mt)
            #pragma unroll
            for (int r = 0; r < 4; ++r) s += acc[mt][r];
        s += __shfl_xor(s, 16);
        s += __shfl_xor(s, 32);
        const float mean = s * (1.f / 64.f);
        float v = 0.f;
        #pragma unroll
        for (int mt = 0; mt < 4; ++mt)
            #pragma unroll
            for (int r = 0; r < 4; ++r) { float d = acc[mt][r] - mean; v = fmaf(d, d, v); }
        v += __shfl_xor(v, 16);
        v += __shfl_xor(v, 32);
        const float rs = 1.f / sqrtf(v * (1.f / 64.f) + 1e-5f);

        #pragma unroll
        for (int mt = 0; mt < 4; ++mt) {
            f32x4 x;
            #pragma unroll
            for (int r = 0; r < 4; ++r)
                x[r] = fmaxf(fmaf((acc[mt][r] - mean) * rs, gv[mt][r], bev[mt][r]), 0.f);
            *(f32x4*)&ldsw[bl * 68 + 16 * mt + 4 * q] = x;
        }

        f32x4 d0 = {0.f,0.f,0.f,0.f}, d1 = {0.f,0.f,0.f,0.f};
        #pragma unroll
        for (int ks2 = 0; ks2 < 2; ++ks2) {
            f32x4 c0 = *(const f32x4*)&ldsw[bl * 68 + 32 * ks2 + 8 * q];
            f32x4 c1 = *(const f32x4*)&ldsw[bl * 68 + 32 * ks2 + 8 * q + 4];
            float vv[8] = {c0[0], c0[1], c0[2], c0[3], c1[0], c1[1], c1[2], c1[3]};
            s16x8 chh, chl; pack8(vv, chh, chl);
            d0 = mfma16(w2h[0][ks2], chh, d0);
            d0 = mfma16(w2h[0][ks2], chl, d0);
            d0 = mfma16(w2l[0][ks2], chh, d0);
            d1 = mfma16(w2h[1][ks2], chh, d1);
            d1 = mfma16(w2h[1][ks2], chl, d1);
            d1 = mfma16(w2l[1][ks2], chh, d1);
        }
        d0 += b2v[0];
        d1 += b2v[1];

        float ss = 0.f;
        #pragma unroll
        for (int r = 0; r < 4; ++r) { ss = fmaf(d0[r], d0[r], ss); ss = fmaf(d1[r], d1[r], ss); }
        ss += __shfl_xor(ss, 16);
        ss += __shfl_xor(ss, 32);
        const float inv   = 1.f / fmaxf(sqrtf(ss), 1e-12f);
        const float scale = (gate >= 0.3f) ? gate * inv : 0.f;

        float* op = out + (size_t)bg * 672 + t * 32;
        f32x4 o0, o1;
        #pragma unroll
        for (int r = 0; r < 4; ++r) { o0[r] = d0[r] * scale; o1[r] = d1[r] * scale; }
        *(f32x4*)(op + 4 * q)      = o0;
        *(f32x4*)(op + 16 + 4 * q) = o1;
    }
}

extern "C" void kernel_launch(void* const* d_in, const int* in_sizes, int n_in,
                              void* d_out, int out_size, void* d_ws, size_t ws_size,
                              hipStream_t stream) {
    const float* z      = (const float*)d_in[0];
    const float* gen_W1 = (const float*)d_in[1];
    const float* gen_b1 = (const float*)d_in[2];
    const float* gen_g  = (const float*)d_in[3];
    const float* gen_be = (const float*)d_in[4];
    const float* gen_W2 = (const float*)d_in[5];
    const float* gen_b2 = (const float*)d_in[6];
    const float* cf_W1  = (const float*)d_in[7];
    const float* cf_b1  = (const float*)d_in[8];
    const float* cf_W2  = (const float*)d_in[9];
    const float* cf_b2  = (const float*)d_in[10];
    const float* g_W    = (const float*)d_in[11];
    const float* g_b    = (const float*)d_in[12];
    const float* c_W1   = (const float*)d_in[13];
    const float* c_b1   = (const float*)d_in[14];
    const float* c_g    = (const float*)d_in[15];
    const float* c_be   = (const float*)d_in[16];
    const float* c_W2   = (const float*)d_in[17];
    const float* c_b2   = (const float*)d_in[18];

    char* wsb = (char*)d_ws;
    uint4* trHI  = (uint4*)(wsb + OFF_TRHI);
    uint4* trLO  = (uint4*)(wsb + OFF_TRLO);
    float* conf  = (float*)(wsb + OFF_CONF);
    float* part  = (float*)(wsb + OFF_PART);
    float* gates = (float*)(wsb + OFF_GATE);
    uint4* w1fh  = (uint4*)(wsb + OFF_W1H);
    uint4* w1fl  = (uint4*)(wsb + OFF_W1L);
    uint4* w2fh  = (uint4*)(wsb + OFF_W2H);
    uint4* w2fl  = (uint4*)(wsb + OFF_W2L);
    uint4* g2h   = (uint4*)(wsb + OFF_G2H);
    uint4* g2l   = (uint4*)(wsb + OFF_G2L);

    float* outp = (float*)d_out;
    float* out2 = outp + (size_t)NB * 672;

    // d_out scratch overlay (consumed before colC overwrites the composed region)
    uint4* actHI = (uint4*)outp;                          // 58,720,256 B
    uint4* actLO = actHI + (size_t)7 * NB * 8;            // 58,720,256 B
    float* tn_ws = outp + (size_t)29360128;               // 58,720,256 B, ends at NB*672*4

    colP<<<dim3(28), dim3(256), 0, stream>>>(
        c_W1, c_W2, gen_W2, w1fh, w1fl, w2fh, w2fl, g2h, g2l);
    colA1<<<dim3(7 * 256), dim3(256), 0, stream>>>(
        z, gen_W1, gen_b1, gen_g, gen_be, cf_W1, cf_b1, cf_W2, cf_b2,
        actHI, actLO, conf);
    colA2<<<dim3(7 * 64), dim3(256), 0, stream>>>(
        actHI, actLO, g2h, g2l, gen_b2, tn_ws);
    colB1<<<dim3(7 * 256), dim3(256), 0, stream>>>(
        tn_ws, g_W, trHI, trLO, part);
    colB2<<<dim3(256), dim3(256), 0, stream>>>(g_b, part, conf, gates, out2);
    colC<<<dim3(21 * 64), dim3(256), 0, stream>>>(
        trHI, trLO, gates, w1fh, w1fl, w2fh, w2fl,
        c_b1, c_g, c_be, c_b2, outp);
}